// Round 14
// baseline (300.328 us; speedup 1.0000x reference)
//
#include <hip/hip_runtime.h>

typedef __attribute__((ext_vector_type(8))) short short8;
typedef __attribute__((ext_vector_type(4))) float f32x4;
typedef __attribute__((ext_vector_type(4))) unsigned short u16x4;

#define B_   2
#define C_   192
#define NH_  4
#define HD_  48
#define CO_  576
#define HGT_ 256
#define WID_ 256
#define NSP_ 65536

__device__ __forceinline__ unsigned short f2bf(float f) {
  unsigned int u = __float_as_uint(f);
  u += 0x7FFFu + ((u >> 16) & 1u);   // RNE; inputs are normal floats
  return (unsigned short)(u >> 16);
}
__device__ __forceinline__ float bf2f(unsigned short h) {
  return __uint_as_float(((unsigned int)h) << 16);
}
__device__ __forceinline__ int swz(int n) { return (n & 7) ^ ((n >> 3) & 7); }

// ---------------------------------------------------------------- K0a: qkv_w fp32 -> bf16, permuted to MFMA-fragment-linear order
// A_perm[(((m>>4)*6 + (k>>5))*4 + ((k>>3)&3))*16 + (m&15)]*8 + (k&7)] = A[m][k]
__global__ void k_cvtA(const float* __restrict__ src, unsigned short* __restrict__ dst) {
  int i = blockIdx.x * 256 + threadIdx.x;
  if (i >= CO_ * C_) return;
  int m = i / C_, k = i % C_;
  int f = m >> 4, l15 = m & 15, kk = k >> 5, lg = (k >> 3) & 3, j = k & 7;
  dst[((((f * 6 + kk) * 4 + lg) * 16 + l15) << 3) + j] = f2bf(src[i]);
}

// ---------------------------------------------------------------- GEMM: out[b][m][n] = sum_k A[m][k] * X[b][k+chanOff][n]
// NWAVES waves cover M = NWAVES*48 rows (K1: 12 waves/768thr = all 576 m ->
// X delivered ONCE per tile, no sibling redundancy. K5: 4 waves = 192 m).
// A-fragments hoisted into registers once per block; TPB consecutive BN=64
// tiles amortize them. Direct u16x4/f32x4 stores (32B per 4-lane group —
// r4-r6 counters show no write amplification; LDS epilogue unnecessary).
// launch_bounds: NWAVES=12 -> (768,3): VGPR cap 170, live ~165 (r12 lesson:
// do NOT cap below live set or af spills to scratch).
template<int NWAVES, int TPB, bool X_BF16, bool OUT_BF16>
__global__ __launch_bounds__(NWAVES * 64, NWAVES == 12 ? 3 : 2)
void k_gemm(const unsigned short* __restrict__ Aperm, long aBatchStride,
            const void* __restrict__ Xin, long xBatchStride, int xChanOff,
            void* __restrict__ Out, long outBatchStride)
{
  constexpr int T = NWAVES * 64;               // threads
  constexpr int S = 12288 / (16 * T);          // 4x4 subtiles per thread (768->1, 256->3)
  constexpr int KG = T >> 4;                   // 4k-groups covered per subtile pass
  constexpr int NSETX = (1024 / TPB) / 8;      // n-sets per XCD
  __shared__ unsigned short Xs[64 * 192];      // Xs[n][k], 16B-unit XOR swizzle
  const int tid = threadIdx.x;
  const int b = blockIdx.z;
  int nset;
  {
    int orig = blockIdx.x;                     // HW round-robins orig%8 across XCDs
    int xcd = orig & 7, wid = orig >> 3;
    nset = xcd * NSETX + wid;
  }

  const int sn = tid & 15, sk = tid >> 4;      // staging: 4n-seg x 4k-grp subtiles
  const int n0 = sn * 4;
  const float* Xf = (const float*)Xin + (size_t)b * xBatchStride + (size_t)xChanOff * NSP_;
  const unsigned short* Xh = (const unsigned short*)Xin + (size_t)b * xBatchStride + (size_t)xChanOff * NSP_;

  const int wave = tid >> 6, lane = tid & 63;
  const int l15 = lane & 15, lg = lane >> 4;
  const int fragM0 = wave * 3;                 // A frag index base (16-row units)
  const unsigned short* Ap = Aperm + (size_t)b * aBatchStride;

  // ---- hoisted A fragments: loaded ONCE, reused for all TPB tiles
  short8 af[6][3];
#pragma unroll
  for (int kk = 0; kk < 6; kk++)
#pragma unroll
    for (int fm = 0; fm < 3; fm++)
      af[kk][fm] = *(const short8*)(Ap + (((size_t)((fragM0 + fm) * 6 + kk) * 64 + lane) << 3));

  f32x4 rf[S][4];
  u16x4 rh[S][4];
  auto LOADT = [&](int nb) {                   // issue loads for tile nb
    const size_t cb = (size_t)nb * 64 + n0;
#pragma unroll
    for (int it = 0; it < S; it++) {
      const int krow = (it * KG + sk) * 4;
      if (!X_BF16) {
        const float* p = Xf + (size_t)krow * NSP_ + cb;
#pragma unroll
        for (int r = 0; r < 4; r++) rf[it][r] = *(const f32x4*)(p + (size_t)r * NSP_);
      } else {
        const unsigned short* p = Xh + (size_t)krow * NSP_ + cb;
#pragma unroll
        for (int r = 0; r < 4; r++) rh[it][r] = *(const u16x4*)(p + (size_t)r * NSP_);
      }
    }
  };
  auto WRITEC = [&]() {                        // 4x4 transpose (+cvt) -> Xs[n][k] (swizzled)
#pragma unroll
    for (int it = 0; it < S; it++) {
      const int g = it * KG + sk;              // 4k-group index 0..47
      const int u16v = g >> 1, hh = g & 1;
#pragma unroll
      for (int j = 0; j < 4; j++) {
        int n = n0 + j;
        u16x4 w;
        if (!X_BF16) { w[0] = f2bf(rf[it][0][j]); w[1] = f2bf(rf[it][1][j]);
                       w[2] = f2bf(rf[it][2][j]); w[3] = f2bf(rf[it][3][j]); }
        else         { w[0] = rh[it][0][j]; w[1] = rh[it][1][j];
                       w[2] = rh[it][2][j]; w[3] = rh[it][3][j]; }
        *(u16x4*)&Xs[n * 192 + ((u16v ^ swz(n)) << 3) + (hh << 2)] = w;
      }
    }
  };

  LOADT(nset * TPB);                           // prologue
  for (int t = 0; t < TPB; t++) {
    const int nb = nset * TPB + t;
    WRITEC();                                  // counted vmcnt wait on rf/rh here
    asm volatile("s_waitcnt lgkmcnt(0)" ::: "memory");
    __builtin_amdgcn_s_barrier();
    if (t + 1 < TPB) LOADT(nb + 1);            // prefetch stays in flight across compute

    f32x4 acc[3][4];
#pragma unroll
    for (int i = 0; i < 3; i++)
#pragma unroll
      for (int j = 0; j < 4; j++) acc[i][j] = (f32x4){0.f, 0.f, 0.f, 0.f};

#pragma unroll
    for (int kk = 0; kk < 6; kk++) {
      const int ur = kk * 4 + lg;
      short8 bfr[4];
#pragma unroll
      for (int fn = 0; fn < 4; fn++) {
        int col = fn * 16 + l15;
        bfr[fn] = *(const short8*)(&Xs[col * 192 + ((ur ^ swz(col)) << 3)]);
      }
      __builtin_amdgcn_s_setprio(1);
#pragma unroll
      for (int fm = 0; fm < 3; fm++)
#pragma unroll
        for (int fn = 0; fn < 4; fn++)   // swapped operands: D rows = n, cols = m
          acc[fm][fn] = __builtin_amdgcn_mfma_f32_16x16x32_bf16(bfr[fn], af[kk][fm], acc[fm][fn], 0, 0, 0);
      __builtin_amdgcn_s_setprio(0);
    }

    // D layout (swapped): lane l15 = m-row (in frag), lg*4+r = n-col.
    // Stores: 4 lanes (same l15, lg 0..3) cover 32B contiguous -> L2 merges.
    const size_t ncol0 = (size_t)nb * 64;
    if (OUT_BF16) {
      unsigned short* O = (unsigned short*)Out + (size_t)b * outBatchStride;
#pragma unroll
      for (int fm = 0; fm < 3; fm++) {
        int m = (fragM0 + fm) * 16 + l15;
#pragma unroll
        for (int fn = 0; fn < 4; fn++) {
          u16x4 w;
          w[0] = f2bf(acc[fm][fn][0]); w[1] = f2bf(acc[fm][fn][1]);
          w[2] = f2bf(acc[fm][fn][2]); w[3] = f2bf(acc[fm][fn][3]);
          *(u16x4*)(O + (size_t)m * NSP_ + ncol0 + fn * 16 + lg * 4) = w;
        }
      }
    } else {
      float* O = (float*)Out + (size_t)b * outBatchStride;
#pragma unroll
      for (int fm = 0; fm < 3; fm++) {
        int m = (fragM0 + fm) * 16 + l15;
#pragma unroll
        for (int fn = 0; fn < 4; fn++)
          *(f32x4*)(O + (size_t)m * NSP_ + ncol0 + fn * 16 + lg * 4) = acc[fm][fn];
      }
    }

    asm volatile("s_waitcnt lgkmcnt(0)" ::: "memory");   // my ds_reads retired
    __builtin_amdgcn_s_barrier();              // all waves done reading Xs
  }
}

// ---------------------------------------------------------------- K2: depthwise 3x3 (pad 1) + sumsq of q,k channels
// LDS-staged strip: 34 raw bf16 rows (18.5 KB), 5 independent 16B
// loads/thread, then each thread computes 4 rows x 8 cols from LDS.
#define DW_RB 32
__global__ __launch_bounds__(256, 6)
void k_dw(const unsigned short* __restrict__ qkv, const float* __restrict__ dww,
          unsigned short* __restrict__ out, float* __restrict__ sumsq)
{
  __shared__ unsigned short rows[34][272];   // data at cols [8..264), halos at 7 and 264
  const int ch = blockIdx.y;
  const int b  = blockIdx.z;
  const int tid = threadIdx.x;
  const int ybase = blockIdx.x * DW_RB;

  const unsigned short* in = qkv + ((size_t)b * CO_ + ch) * NSP_;
  unsigned short* o = out + ((size_t)b * CO_ + ch) * NSP_;
  float w[9];
#pragma unroll
  for (int i = 0; i < 9; i++) w[i] = dww[ch * 9 + i];

  short8 st[5];
#pragma unroll
  for (int i = 0; i < 5; i++) {
    int u = tid + i * 256;
    if (u < 1088) {
      int r = u >> 5, sg = u & 31;
      int yy = ybase - 1 + r;
      short8 z = {0, 0, 0, 0, 0, 0, 0, 0};
      if ((unsigned)yy < (unsigned)HGT_) z = *(const short8*)(in + (size_t)yy * WID_ + sg * 8);
      st[i] = z;
    }
  }
#pragma unroll
  for (int i = 0; i < 5; i++) {
    int u = tid + i * 256;
    if (u < 1088) {
      int r = u >> 5, sg = u & 31;
      *(short8*)&rows[r][8 + sg * 8] = st[i];
    }
  }
  if (tid < 68) rows[tid >> 1][(tid & 1) ? 264 : 7] = 0;   // zero halo cols
  __syncthreads();

  const int seg = tid & 31, rowblk = tid >> 5;
  const int c0 = 8 + seg * 8;
  float win[3][10];
  float ss = 0.f;
#pragma unroll
  for (int i = 0; i < 6; i++) {
    const int lr = rowblk * 4 + i;
    float* f = win[i % 3];
    short8 v = *(const short8*)&rows[lr][c0];
#pragma unroll
    for (int j = 0; j < 8; j++) f[j + 1] = bf2f((unsigned short)v[j]);
    f[0] = bf2f(rows[lr][c0 - 1]);
    f[9] = bf2f(rows[lr][c0 + 8]);
    if (i >= 2) {
      const float* a  = win[(i - 2) % 3];
      const float* bb = win[(i - 1) % 3];
      const float* cc = f;
      short8 ov;
#pragma unroll
      for (int j = 0; j < 8; j++) {
        float acc = a[j]  * w[0] + a[j + 1]  * w[1] + a[j + 2]  * w[2]
                  + bb[j] * w[3] + bb[j + 1] * w[4] + bb[j + 2] * w[5]
                  + cc[j] * w[6] + cc[j + 1] * w[7] + cc[j + 2] * w[8];
        ov[j] = (short)f2bf(acc);
        ss += acc * acc;
      }
      *(short8*)(o + (size_t)(ybase + rowblk * 4 + i - 2) * WID_ + seg * 8) = ov;
    }
  }

  if (ch < 2 * C_) {                          // only q,k channels need norms
#pragma unroll
    for (int off = 32; off > 0; off >>= 1) ss += __shfl_down(ss, off);
    __shared__ float wsum[4];
    if ((tid & 63) == 0) wsum[tid >> 6] = ss;
    __syncthreads();
    if (tid == 0) atomicAdd(&sumsq[b * 2 * C_ + ch], wsum[0] + wsum[1] + wsum[2] + wsum[3]);
  }
}

// ---------------------------------------------------------------- K3: per-(b,h) q.k^T partials over n-chunks (MFMA)
__global__ __launch_bounds__(256)
void k_qk(const unsigned short* __restrict__ qkvd, float* __restrict__ part)
{
  const int chunk = blockIdx.x;               // 64 chunks of 1024 n
  const int h = blockIdx.y, b = blockIdx.z;
  const int tid = threadIdx.x;
  const int wave = tid >> 6, lane = tid & 63;
  const int l15 = lane & 15, lg = lane >> 4;
  const unsigned short* qb = qkvd + (size_t)b * CO_ * NSP_ + (size_t)(h * HD_) * NSP_;
  const unsigned short* kb = qkvd + (size_t)b * CO_ * NSP_ + (size_t)(C_ + h * HD_) * NSP_;
  const int kbase = chunk * 1024 + wave * 256;

  f32x4 acc[3][3];
#pragma unroll
  for (int i = 0; i < 3; i++)
#pragma unroll
    for (int j = 0; j < 3; j++) acc[i][j] = (f32x4){0.f, 0.f, 0.f, 0.f};

#pragma unroll
  for (int ks = 0; ks < 8; ks++) {
    const int k0 = kbase + ks * 32 + lg * 8;
    short8 af[3], bfr[3];
#pragma unroll
    for (int i = 0; i < 3; i++)
      af[i] = *(const short8*)(qb + (size_t)(i * 16 + l15) * NSP_ + k0);
#pragma unroll
    for (int i = 0; i < 3; i++)
      bfr[i] = *(const short8*)(kb + (size_t)(i * 16 + l15) * NSP_ + k0);
#pragma unroll
    for (int fm = 0; fm < 3; fm++)
#pragma unroll
      for (int fn = 0; fn < 3; fn++)
        acc[fm][fn] = __builtin_amdgcn_mfma_f32_16x16x32_bf16(af[fm], bfr[fn], acc[fm][fn], 0, 0, 0);
  }

  __shared__ float red[4][HD_ * HD_];
#pragma unroll
  for (int fm = 0; fm < 3; fm++)
#pragma unroll
    for (int fn = 0; fn < 3; fn++)
#pragma unroll
      for (int r = 0; r < 4; r++)
        red[wave][(fm * 16 + lg * 4 + r) * HD_ + fn * 16 + l15] = acc[fm][fn][r];
  __syncthreads();

  float* P = part + ((size_t)(b * NH_ + h) * 64 + chunk) * (HD_ * HD_);
#pragma unroll
  for (int j = 0; j < 9; j++) {               // 2304 = 9*256
    int e = tid + j * 256;
    P[e] = red[0][e] + red[1][e] + red[2][e] + red[3][e];
  }
}

// ---------------------------------------------------------------- K4: reduce 64 partials, scale, softmax,
//      compose M[b] = proj_w @ blockdiag(attn), stored fragment-permuted bf16
__global__ __launch_bounds__(256)
void k_smax(const float* __restrict__ part, const float* __restrict__ sumsq,
            const float* __restrict__ temp, const float* __restrict__ projw,
            unsigned short* __restrict__ M)
{
  const int h = blockIdx.x, b = blockIdx.y;
  const int tid = threadIdx.x;
  __shared__ float lgt[HD_][HD_];
  __shared__ float at[HD_][HD_];
  __shared__ float pw[C_][HD_];
  const float tmp = temp[h];
  const float* P = part + (size_t)(b * NH_ + h) * 64 * (HD_ * HD_);

  float s[9];
#pragma unroll
  for (int j = 0; j < 9; j++) s[j] = 0.f;
  for (int p = 0; p < 64; p++) {
    const float* Pp = P + (size_t)p * (HD_ * HD_);
#pragma unroll
    for (int j = 0; j < 9; j++) s[j] += Pp[tid + j * 256];
  }
#pragma unroll
  for (int j = 0; j < 9; j++) {
    int e = tid + j * 256;
    int c = e / HD_, d = e % HD_;
    float nq = fmaxf(sqrtf(sumsq[b * 2 * C_ + h * HD_ + c]), 1e-12f);
    float nk = fmaxf(sqrtf(sumsq[b * 2 * C_ + C_ + h * HD_ + d]), 1e-12f);
    lgt[c][d] = s[j] / (nq * nk) * tmp;
  }
  for (int e = tid; e < C_ * HD_; e += 256) {
    int o = e / HD_, c = e % HD_;
    pw[o][c] = projw[o * C_ + h * HD_ + c];
  }
  __syncthreads();
  if (tid < HD_) {
    float mx = -1e30f;
    for (int d = 0; d < HD_; d++) mx = fmaxf(mx, lgt[tid][d]);
    float ssum = 0.f;
    for (int d = 0; d < HD_; d++) { float e_ = expf(lgt[tid][d] - mx); at[tid][d] = e_; ssum += e_; }
    float inv = 1.f / ssum;
    for (int d = 0; d < HD_; d++) at[tid][d] *= inv;
  }
  __syncthreads();
  unsigned short* Mo = M + (size_t)b * C_ * C_;
  for (int e = tid; e < C_ * HD_; e += 256) {
    int o = e / HD_, d = e % HD_;
    float sm = 0.f;
    for (int c = 0; c < HD_; c++) sm += pw[o][c] * at[c][d];
    int col = h * HD_ + d;                    // fragment-permuted index (see k_cvtA)
    int f = o >> 4, l15 = o & 15, kk = col >> 5, lg = (col >> 3) & 3, j = col & 7;
    Mo[((((f * 6 + kk) * 4 + lg) * 16 + l15) << 3) + j] = f2bf(sm);
  }
}

// ----------------------------------------------------------------
extern "C" void kernel_launch(void* const* d_in, const int* in_sizes, int n_in,
                              void* d_out, int out_size, void* d_ws, size_t ws_size,
                              hipStream_t stream)
{
  const float* x     = (const float*)d_in[0];
  const float* qkvw  = (const float*)d_in[1];
  const float* dww   = (const float*)d_in[2];
  const float* projw = (const float*)d_in[3];
  const float* temp  = (const float*)d_in[4];
  float* out         = (float*)d_out;

  char* ws = (char*)d_ws;
  size_t off = 0;
  auto alloc = [&](size_t bytes) { void* p = ws + off; off += (bytes + 255) & ~(size_t)255; return p; };
  unsigned short* qkvd_bf = (unsigned short*)alloc((size_t)B_ * CO_ * NSP_ * 2);
  unsigned short* qkv_bf  = (unsigned short*)alloc((size_t)B_ * CO_ * NSP_ * 2);
  unsigned short* qkvw_bf = (unsigned short*)alloc((size_t)CO_ * C_ * 2);
  unsigned short* M_bf    = (unsigned short*)alloc((size_t)B_ * C_ * C_ * 2);
  float* sumsq            = (float*)alloc((size_t)B_ * 2 * C_ * 4);
  float* part             = (float*)alloc((size_t)B_ * NH_ * 64 * HD_ * HD_ * 4);

  hipMemsetAsync(sumsq, 0, (size_t)B_ * 2 * C_ * 4, stream);
  k_cvtA<<<dim3((CO_ * C_ + 255) / 256), dim3(256), 0, stream>>>(qkvw, qkvw_bf);
  // K1: qkv = qkv_w @ x — 12-wave blocks, all 576 m, X staged once/tile
  //     (128 nsets x 8 tiles; 256 blocks = 1/CU)
  k_gemm<12, 8, false, true><<<dim3(128, 1, B_), dim3(768), 0, stream>>>(
      qkvw_bf, 0, x, (long)C_ * NSP_, 0, qkv_bf, (long)CO_ * NSP_);
  // K2: depthwise 3x3 + q/k sum-of-squares (LDS-staged strip)
  k_dw<<<dim3(HGT_ / DW_RB, CO_, B_), dim3(256), 0, stream>>>(qkv_bf, dww, qkvd_bf, sumsq);
  // K3: q.k^T partials (cross-wave reduced: 64 tiles per (b,h))
  k_qk<<<dim3(64, NH_, B_), dim3(256), 0, stream>>>(qkvd_bf, part);
  // K4: softmax + fold proj_w -> M[b] (192x192 bf16, fragment-permuted)
  k_smax<<<dim3(NH_, B_), dim3(256), 0, stream>>>(part, sumsq, temp, projw, M_bf);
  // K5: out = M[b] @ v — 4-wave blocks, TPB=2 -> 1024 blocks = 4/CU
  k_gemm<4, 2, true, false><<<dim3(512, 1, B_), dim3(256), 0, stream>>>(
      M_bf, (long)C_ * C_, qkvd_bf, (long)CO_ * NSP_, 2 * C_, out, (long)C_ * NSP_);
}

// Round 15
// 223.143 us; speedup vs baseline: 1.3459x; 1.3459x over previous
//
#include <hip/hip_runtime.h>

typedef __attribute__((ext_vector_type(8))) short short8;
typedef __attribute__((ext_vector_type(4))) float f32x4;
typedef __attribute__((ext_vector_type(4))) unsigned short u16x4;

#define B_   2
#define C_   192
#define NH_  4
#define HD_  48
#define CO_  576
#define HGT_ 256
#define WID_ 256
#define NSP_ 65536

__device__ __forceinline__ unsigned short f2bf(float f) {
  unsigned int u = __float_as_uint(f);
  u += 0x7FFFu + ((u >> 16) & 1u);   // RNE; inputs are normal floats
  return (unsigned short)(u >> 16);
}
__device__ __forceinline__ float bf2f(unsigned short h) {
  return __uint_as_float(((unsigned int)h) << 16);
}
__device__ __forceinline__ int swz(int n) { return (n & 7) ^ ((n >> 3) & 7); }

// ---------------------------------------------------------------- K0a: qkv_w fp32 -> bf16, permuted to MFMA-fragment-linear order
// A_perm[(((m>>4)*6 + (k>>5))*4 + ((k>>3)&3))*16 + (m&15)]*8 + (k&7)] = A[m][k]
__global__ void k_cvtA(const float* __restrict__ src, unsigned short* __restrict__ dst) {
  int i = blockIdx.x * 256 + threadIdx.x;
  if (i >= CO_ * C_) return;
  int m = i / C_, k = i % C_;
  int f = m >> 4, l15 = m & 15, kk = k >> 5, lg = (k >> 3) & 3, j = k & 7;
  dst[((((f * 6 + kk) * 4 + lg) * 16 + l15) << 3) + j] = f2bf(src[i]);
}

// ---------------------------------------------------------------- GEMM: out[b][m][n] = sum_k A[m][k] * X[b][k+chanOff][n]
// A-fragments HOISTED into registers once per block (18 x short8); TPB
// consecutive BN=64 tiles per block amortize them. X fp32 (converted in
// WRITEC) or bf16. bf16 C-writes go through an LDS epilogue (128 B pieces).
// 256 thr = 4 waves (4m x 1n), BM=192, full K=192 per tile in LDS.
// NOTE: launch_bounds MUST stay (256,2): live set ~120-150 VGPR; capping
// lower (r12: (256,3) -> 84; r14: 768-thr -> 84) spills af to scratch
// (FETCH +100 MB, 2x slowdown). VGPR 124, no spill, is the verified state.
template<int MBLOCKS, int TPB, bool X_BF16, bool OUT_BF16>
__global__ __launch_bounds__(256, 2)
void k_gemm(const unsigned short* __restrict__ Aperm, long aBatchStride,
            const void* __restrict__ Xin, long xBatchStride, int xChanOff,
            void* __restrict__ Out, long outBatchStride)
{
  constexpr int NSETX = 1024 / TPB / 8;        // n-sets per XCD
  __shared__ unsigned short Xs[192 * 72];      // 27.6 KB union: staging [64][192] / epilogue [192][72]
  const int tid = threadIdx.x;
  const int b = blockIdx.z;
  int mb, nset;
  {
    int orig = blockIdx.x;                     // HW round-robins orig%8 across XCDs
    int xcd = orig & 7, wid = orig >> 3;
    if (MBLOCKS == 3) { mb = wid % 3; nset = xcd * NSETX + wid / 3; }  // 3 siblings co-XCD, lockstep tiles
    else              { mb = 0;       nset = xcd * NSETX + wid; }
  }

  const int sn = tid & 15, sk = tid >> 4;      // staging: 4n-seg x 4k-grp subtiles
  const int n0 = sn * 4, hh = sk & 1;
  const float* Xf = (const float*)Xin + (size_t)b * xBatchStride + (size_t)xChanOff * NSP_;
  const unsigned short* Xh = (const unsigned short*)Xin + (size_t)b * xBatchStride + (size_t)xChanOff * NSP_;

  const int wave = tid >> 6, lane = tid & 63;
  const int l15 = lane & 15, lg = lane >> 4;
  const int fragM0 = mb * 12 + wave * 3;       // A frag index base (16-row units)
  const unsigned short* Ap = Aperm + (size_t)b * aBatchStride;

  // ---- hoisted A fragments: loaded ONCE, reused for all TPB tiles
  short8 af[6][3];
#pragma unroll
  for (int kk = 0; kk < 6; kk++)
#pragma unroll
    for (int fm = 0; fm < 3; fm++)
      af[kk][fm] = *(const short8*)(Ap + (((size_t)((fragM0 + fm) * 6 + kk) * 64 + lane) << 3));

  f32x4 rf[3][4];
  u16x4 rh[3][4];
  auto LOADT = [&](int nb) {                   // issue 12 loads for tile nb
    const size_t cb = (size_t)nb * 64 + n0;
#pragma unroll
    for (int it = 0; it < 3; it++) {
      if (!X_BF16) {
        const float* p = Xf + (size_t)(it * 64 + sk * 4) * NSP_ + cb;
#pragma unroll
        for (int r = 0; r < 4; r++) rf[it][r] = *(const f32x4*)(p + (size_t)r * NSP_);
      } else {
        const unsigned short* p = Xh + (size_t)(it * 64 + sk * 4) * NSP_ + cb;
#pragma unroll
        for (int r = 0; r < 4; r++) rh[it][r] = *(const u16x4*)(p + (size_t)r * NSP_);
      }
    }
  };
  auto WRITEC = [&]() {                        // 4x4 transpose (+cvt) -> Xs[n][k] (swizzled)
#pragma unroll
    for (int it = 0; it < 3; it++) {
      const int u16v = it * 8 + (sk >> 1);
#pragma unroll
      for (int j = 0; j < 4; j++) {
        int n = n0 + j;
        u16x4 w;
        if (!X_BF16) { w[0] = f2bf(rf[it][0][j]); w[1] = f2bf(rf[it][1][j]);
                       w[2] = f2bf(rf[it][2][j]); w[3] = f2bf(rf[it][3][j]); }
        else         { w[0] = rh[it][0][j]; w[1] = rh[it][1][j];
                       w[2] = rh[it][2][j]; w[3] = rh[it][3][j]; }
        *(u16x4*)&Xs[n * 192 + ((u16v ^ swz(n)) << 3) + (hh << 2)] = w;
      }
    }
  };

  LOADT(nset * TPB);                           // prologue
  for (int t = 0; t < TPB; t++) {
    const int nb = nset * TPB + t;
    WRITEC();                                  // counted vmcnt wait on rf/rh here
    asm volatile("s_waitcnt lgkmcnt(0)" ::: "memory");
    __builtin_amdgcn_s_barrier();
    if (t + 1 < TPB) LOADT(nb + 1);            // prefetch stays in flight across compute

    f32x4 acc[3][4];
#pragma unroll
    for (int i = 0; i < 3; i++)
#pragma unroll
      for (int j = 0; j < 4; j++) acc[i][j] = (f32x4){0.f, 0.f, 0.f, 0.f};

#pragma unroll
    for (int kk = 0; kk < 6; kk++) {
      const int ur = kk * 4 + lg;
      short8 bfr[4];
#pragma unroll
      for (int fn = 0; fn < 4; fn++) {
        int col = fn * 16 + l15;
        bfr[fn] = *(const short8*)(&Xs[col * 192 + ((ur ^ swz(col)) << 3)]);
      }
      __builtin_amdgcn_s_setprio(1);
#pragma unroll
      for (int fm = 0; fm < 3; fm++)
#pragma unroll
        for (int fn = 0; fn < 4; fn++)   // swapped operands: D rows = n, cols = m
          acc[fm][fn] = __builtin_amdgcn_mfma_f32_16x16x32_bf16(bfr[fn], af[kk][fm], acc[fm][fn], 0, 0, 0);
      __builtin_amdgcn_s_setprio(0);
    }

    if (OUT_BF16) {
      // LDS epilogue: repack so each store piece is 128 B contiguous per row
      asm volatile("s_waitcnt lgkmcnt(0)" ::: "memory");
      __builtin_amdgcn_s_barrier();            // all waves done reading Xs
#pragma unroll
      for (int fm = 0; fm < 3; fm++) {
        int mloc = (wave * 3 + fm) * 16 + l15;
#pragma unroll
        for (int fn = 0; fn < 4; fn++) {
          u16x4 w;
          w[0] = f2bf(acc[fm][fn][0]); w[1] = f2bf(acc[fm][fn][1]);
          w[2] = f2bf(acc[fm][fn][2]); w[3] = f2bf(acc[fm][fn][3]);
          *(u16x4*)&Xs[mloc * 72 + fn * 16 + lg * 4] = w;
        }
      }
      asm volatile("s_waitcnt lgkmcnt(0)" ::: "memory");
      __builtin_amdgcn_s_barrier();
      unsigned short* O = (unsigned short*)Out + (size_t)b * outBatchStride +
                          (size_t)mb * 192 * NSP_ + (size_t)nb * 64;
#pragma unroll
      for (int i = 0; i < 6; i++) {            // 192 rows x 128 B, 16 B/lane
        int p = tid + i * 256, row = p >> 3, cB = (p & 7) * 8;
        short8 v = *(const short8*)&Xs[row * 72 + cB];
        *(short8*)(O + (size_t)row * NSP_ + cB) = v;
      }
      asm volatile("s_waitcnt lgkmcnt(0)" ::: "memory");
      __builtin_amdgcn_s_barrier();            // LDS reads retired before next WRITEC
    } else {
      float* O = (float*)Out + (size_t)b * outBatchStride;
      const size_t ncol0 = (size_t)nb * 64;
#pragma unroll
      for (int fm = 0; fm < 3; fm++) {
        int m = (fragM0 + fm) * 16 + l15;
#pragma unroll
        for (int fn = 0; fn < 4; fn++)
          *(f32x4*)(O + (size_t)m * NSP_ + ncol0 + fn * 16 + lg * 4) = acc[fm][fn];
      }
      asm volatile("s_waitcnt lgkmcnt(0)" ::: "memory");
      __builtin_amdgcn_s_barrier();
    }
  }
}

// ---------------------------------------------------------------- K2: depthwise 3x3 (pad 1) + sumsq of q,k channels
// LDS-staged strip: 34 raw bf16 rows (18.5 KB), 5 independent 16B
// loads/thread, then each thread computes 4 rows x 8 cols from LDS.
#define DW_RB 32
__global__ __launch_bounds__(256, 6)
void k_dw(const unsigned short* __restrict__ qkv, const float* __restrict__ dww,
          unsigned short* __restrict__ out, float* __restrict__ sumsq)
{
  __shared__ unsigned short rows[34][272];   // data at cols [8..264), halos at 7 and 264
  const int ch = blockIdx.y;
  const int b  = blockIdx.z;
  const int tid = threadIdx.x;
  const int ybase = blockIdx.x * DW_RB;

  const unsigned short* in = qkv + ((size_t)b * CO_ + ch) * NSP_;
  unsigned short* o = out + ((size_t)b * CO_ + ch) * NSP_;
  float w[9];
#pragma unroll
  for (int i = 0; i < 9; i++) w[i] = dww[ch * 9 + i];

  short8 st[5];
#pragma unroll
  for (int i = 0; i < 5; i++) {
    int u = tid + i * 256;
    if (u < 1088) {
      int r = u >> 5, sg = u & 31;
      int yy = ybase - 1 + r;
      short8 z = {0, 0, 0, 0, 0, 0, 0, 0};
      if ((unsigned)yy < (unsigned)HGT_) z = *(const short8*)(in + (size_t)yy * WID_ + sg * 8);
      st[i] = z;
    }
  }
#pragma unroll
  for (int i = 0; i < 5; i++) {
    int u = tid + i * 256;
    if (u < 1088) {
      int r = u >> 5, sg = u & 31;
      *(short8*)&rows[r][8 + sg * 8] = st[i];
    }
  }
  if (tid < 68) rows[tid >> 1][(tid & 1) ? 264 : 7] = 0;   // zero halo cols
  __syncthreads();

  const int seg = tid & 31, rowblk = tid >> 5;
  const int c0 = 8 + seg * 8;
  float win[3][10];
  float ss = 0.f;
#pragma unroll
  for (int i = 0; i < 6; i++) {
    const int lr = rowblk * 4 + i;
    float* f = win[i % 3];
    short8 v = *(const short8*)&rows[lr][c0];
#pragma unroll
    for (int j = 0; j < 8; j++) f[j + 1] = bf2f((unsigned short)v[j]);
    f[0] = bf2f(rows[lr][c0 - 1]);
    f[9] = bf2f(rows[lr][c0 + 8]);
    if (i >= 2) {
      const float* a  = win[(i - 2) % 3];
      const float* bb = win[(i - 1) % 3];
      const float* cc = f;
      short8 ov;
#pragma unroll
      for (int j = 0; j < 8; j++) {
        float acc = a[j]  * w[0] + a[j + 1]  * w[1] + a[j + 2]  * w[2]
                  + bb[j] * w[3] + bb[j + 1] * w[4] + bb[j + 2] * w[5]
                  + cc[j] * w[6] + cc[j + 1] * w[7] + cc[j + 2] * w[8];
        ov[j] = (short)f2bf(acc);
        ss += acc * acc;
      }
      *(short8*)(o + (size_t)(ybase + rowblk * 4 + i - 2) * WID_ + seg * 8) = ov;
    }
  }

  if (ch < 2 * C_) {                          // only q,k channels need norms
#pragma unroll
    for (int off = 32; off > 0; off >>= 1) ss += __shfl_down(ss, off);
    __shared__ float wsum[4];
    if ((tid & 63) == 0) wsum[tid >> 6] = ss;
    __syncthreads();
    if (tid == 0) atomicAdd(&sumsq[b * 2 * C_ + ch], wsum[0] + wsum[1] + wsum[2] + wsum[3]);
  }
}

// ---------------------------------------------------------------- K3: per-(b,h) q.k^T partials over n-chunks (MFMA)
__global__ __launch_bounds__(256)
void k_qk(const unsigned short* __restrict__ qkvd, float* __restrict__ part)
{
  const int chunk = blockIdx.x;               // 64 chunks of 1024 n
  const int h = blockIdx.y, b = blockIdx.z;
  const int tid = threadIdx.x;
  const int wave = tid >> 6, lane = tid & 63;
  const int l15 = lane & 15, lg = lane >> 4;
  const unsigned short* qb = qkvd + (size_t)b * CO_ * NSP_ + (size_t)(h * HD_) * NSP_;
  const unsigned short* kb = qkvd + (size_t)b * CO_ * NSP_ + (size_t)(C_ + h * HD_) * NSP_;
  const int kbase = chunk * 1024 + wave * 256;

  f32x4 acc[3][3];
#pragma unroll
  for (int i = 0; i < 3; i++)
#pragma unroll
    for (int j = 0; j < 3; j++) acc[i][j] = (f32x4){0.f, 0.f, 0.f, 0.f};

#pragma unroll
  for (int ks = 0; ks < 8; ks++) {
    const int k0 = kbase + ks * 32 + lg * 8;
    short8 af[3], bfr[3];
#pragma unroll
    for (int i = 0; i < 3; i++)
      af[i] = *(const short8*)(qb + (size_t)(i * 16 + l15) * NSP_ + k0);
#pragma unroll
    for (int i = 0; i < 3; i++)
      bfr[i] = *(const short8*)(kb + (size_t)(i * 16 + l15) * NSP_ + k0);
#pragma unroll
    for (int fm = 0; fm < 3; fm++)
#pragma unroll
      for (int fn = 0; fn < 3; fn++)
        acc[fm][fn] = __builtin_amdgcn_mfma_f32_16x16x32_bf16(af[fm], bfr[fn], acc[fm][fn], 0, 0, 0);
  }

  __shared__ float red[4][HD_ * HD_];
#pragma unroll
  for (int fm = 0; fm < 3; fm++)
#pragma unroll
    for (int fn = 0; fn < 3; fn++)
#pragma unroll
      for (int r = 0; r < 4; r++)
        red[wave][(fm * 16 + lg * 4 + r) * HD_ + fn * 16 + l15] = acc[fm][fn][r];
  __syncthreads();

  float* P = part + ((size_t)(b * NH_ + h) * 64 + chunk) * (HD_ * HD_);
#pragma unroll
  for (int j = 0; j < 9; j++) {               // 2304 = 9*256
    int e = tid + j * 256;
    P[e] = red[0][e] + red[1][e] + red[2][e] + red[3][e];
  }
}

// ---------------------------------------------------------------- K4: reduce 64 partials, scale, softmax,
//      compose M[b] = proj_w @ blockdiag(attn), stored fragment-permuted bf16
__global__ __launch_bounds__(256)
void k_smax(const float* __restrict__ part, const float* __restrict__ sumsq,
            const float* __restrict__ temp, const float* __restrict__ projw,
            unsigned short* __restrict__ M)
{
  const int h = blockIdx.x, b = blockIdx.y;
  const int tid = threadIdx.x;
  __shared__ float lgt[HD_][HD_];
  __shared__ float at[HD_][HD_];
  __shared__ float pw[C_][HD_];
  const float tmp = temp[h];
  const float* P = part + (size_t)(b * NH_ + h) * 64 * (HD_ * HD_);

  float s[9];
#pragma unroll
  for (int j = 0; j < 9; j++) s[j] = 0.f;
  for (int p = 0; p < 64; p++) {
    const float* Pp = P + (size_t)p * (HD_ * HD_);
#pragma unroll
    for (int j = 0; j < 9; j++) s[j] += Pp[tid + j * 256];
  }
#pragma unroll
  for (int j = 0; j < 9; j++) {
    int e = tid + j * 256;
    int c = e / HD_, d = e % HD_;
    float nq = fmaxf(sqrtf(sumsq[b * 2 * C_ + h * HD_ + c]), 1e-12f);
    float nk = fmaxf(sqrtf(sumsq[b * 2 * C_ + C_ + h * HD_ + d]), 1e-12f);
    lgt[c][d] = s[j] / (nq * nk) * tmp;
  }
  for (int e = tid; e < C_ * HD_; e += 256) {
    int o = e / HD_, c = e % HD_;
    pw[o][c] = projw[o * C_ + h * HD_ + c];
  }
  __syncthreads();
  if (tid < HD_) {
    float mx = -1e30f;
    for (int d = 0; d < HD_; d++) mx = fmaxf(mx, lgt[tid][d]);
    float ssum = 0.f;
    for (int d = 0; d < HD_; d++) { float e_ = expf(lgt[tid][d] - mx); at[tid][d] = e_; ssum += e_; }
    float inv = 1.f / ssum;
    for (int d = 0; d < HD_; d++) at[tid][d] *= inv;
  }
  __syncthreads();
  unsigned short* Mo = M + (size_t)b * C_ * C_;
  for (int e = tid; e < C_ * HD_; e += 256) {
    int o = e / HD_, d = e % HD_;
    float sm = 0.f;
    for (int c = 0; c < HD_; c++) sm += pw[o][c] * at[c][d];
    int col = h * HD_ + d;                    // fragment-permuted index (see k_cvtA)
    int f = o >> 4, l15 = o & 15, kk = col >> 5, lg = (col >> 3) & 3, j = col & 7;
    Mo[((((f * 6 + kk) * 4 + lg) * 16 + l15) << 3) + j] = f2bf(sm);
  }
}

// ----------------------------------------------------------------
extern "C" void kernel_launch(void* const* d_in, const int* in_sizes, int n_in,
                              void* d_out, int out_size, void* d_ws, size_t ws_size,
                              hipStream_t stream)
{
  const float* x     = (const float*)d_in[0];
  const float* qkvw  = (const float*)d_in[1];
  const float* dww   = (const float*)d_in[2];
  const float* projw = (const float*)d_in[3];
  const float* temp  = (const float*)d_in[4];
  float* out         = (float*)d_out;

  char* ws = (char*)d_ws;
  size_t off = 0;
  auto alloc = [&](size_t bytes) { void* p = ws + off; off += (bytes + 255) & ~(size_t)255; return p; };
  unsigned short* qkvd_bf = (unsigned short*)alloc((size_t)B_ * CO_ * NSP_ * 2);
  unsigned short* qkv_bf  = (unsigned short*)alloc((size_t)B_ * CO_ * NSP_ * 2);
  unsigned short* qkvw_bf = (unsigned short*)alloc((size_t)CO_ * C_ * 2);
  unsigned short* M_bf    = (unsigned short*)alloc((size_t)B_ * C_ * C_ * 2);
  float* sumsq            = (float*)alloc((size_t)B_ * 2 * C_ * 4);
  float* part             = (float*)alloc((size_t)B_ * NH_ * 64 * HD_ * HD_ * 4);

  hipMemsetAsync(sumsq, 0, (size_t)B_ * 2 * C_ * 4, stream);
  k_cvtA<<<dim3((CO_ * C_ + 255) / 256), dim3(256), 0, stream>>>(qkvw, qkvw_bf);
  // K1: qkv = qkv_w @ x (fp32 read directly, cvt fused in staging; 768 blocks)
  k_gemm<3, 8, false, true><<<dim3(384, 1, B_), dim3(256), 0, stream>>>(
      qkvw_bf, 0, x, (long)C_ * NSP_, 0, qkv_bf, (long)CO_ * NSP_);
  // K2: depthwise 3x3 + q/k sum-of-squares (LDS-staged strip)
  k_dw<<<dim3(HGT_ / DW_RB, CO_, B_), dim3(256), 0, stream>>>(qkv_bf, dww, qkvd_bf, sumsq);
  // K3: q.k^T partials (cross-wave reduced: 64 tiles per (b,h))
  k_qk<<<dim3(64, NH_, B_), dim3(256), 0, stream>>>(qkvd_bf, part);
  // K4: softmax + fold proj_w -> M[b] (192x192 bf16, fragment-permuted)
  k_smax<<<dim3(NH_, B_), dim3(256), 0, stream>>>(part, sumsq, temp, projw, M_bf);
  // K5: out = M[b] @ v   (256 nsets x 4 tiles; 512 blocks)
  k_gemm<1, 4, true, false><<<dim3(256, 1, B_), dim3(256), 0, stream>>>(
      M_bf, (long)C_ * C_, qkvd_bf, (long)CO_ * NSP_, 2 * C_, out, (long)C_ * NSP_);
}